// Round 8
// baseline (362.890 us; speedup 1.0000x reference)
//
#include <hip/hip_runtime.h>
#include <math.h>

// Problem constants (fixed by the reference setup)
#define NN 50000          // nodes
#define NE 800000         // edges (before self loops)
#define NTE (NE + NN)     // edges incl self loops
#define NG 16             // graphs
#define HID 128           // hidden/out dim (all layers out=128)
#define NEG_SLOPE 0.2f

#define NBUK 391          // ceil(NN/128) buckets of 128 dst nodes
#define EPW 4096          // edges per workgroup in bucket count/scatter
#define NWG_E ((NTE + EPW - 1) / EPW)   // 208

typedef __attribute__((ext_vector_type(8))) __bf16 bf16x8;
typedef __attribute__((ext_vector_type(4))) float f32x4;

union V16 {
    float4 f4;
    bf16x8 b8;
    __bf16 h[8];
};

// ---------------------------------------------------------------------------
// prep: zero bcnt/bwr/sums + all three weight transposes, one dispatch.
// W [K][128] fp32 -> Wt [128][K] bf16
// ---------------------------------------------------------------------------
__global__ void k_prep(int* __restrict__ bcnt, int* __restrict__ bwr,
                       float* __restrict__ sums,
                       const float* __restrict__ W0, const float* __restrict__ W1,
                       const float* __restrict__ W2, __bf16* __restrict__ Wt0,
                       __bf16* __restrict__ Wt1, __bf16* __restrict__ Wt2) {
    int t = blockIdx.x * blockDim.x + threadIdx.x;
    if (t <= NBUK) {
        bcnt[t] = 0;
        bwr[t] = 0;
    }
    if (t < NG * HID) sums[t] = 0.0f;
    if (t < 256 * HID) {
        int k = t >> 7, n = t & 127;
        Wt0[(size_t)n * 256 + k] = (__bf16)W0[t];
    } else if (t < 256 * HID + HID * HID) {
        int u = t - 256 * HID;
        int k = u >> 7, n = u & 127;
        Wt1[(size_t)n * HID + k] = (__bf16)W1[u];
    } else if (t < 256 * HID + 2 * HID * HID) {
        int u = t - 256 * HID - HID * HID;
        int k = u >> 7, n = u & 127;
        Wt2[(size_t)n * HID + k] = (__bf16)W2[u];
    }
}

// ---------------------------------------------------------------------------
// Bucketed CSR build.  rec[] holds src | (dst&127)<<17, grouped by bucket.
// ---------------------------------------------------------------------------
__global__ __launch_bounds__(256) void k_bcnt(const int* __restrict__ ei,
                                              int* __restrict__ bcnt) {
    __shared__ int hist[NBUK];
    int tid = threadIdx.x;
    for (int b = tid; b < NBUK; b += 256) hist[b] = 0;
    __syncthreads();
    int base = blockIdx.x * EPW;
    #pragma unroll
    for (int r = 0; r < EPW / 256; r++) {
        int idx = base + r * 256 + tid;
        if (idx < NTE) {
            int dst = (idx < NE) ? ei[NE + idx] : (idx - NE);
            atomicAdd(&hist[dst >> 7], 1);
        }
    }
    __syncthreads();
    for (int b = tid; b < NBUK; b += 256) {
        int c = hist[b];
        if (c) atomicAdd(&bcnt[b], c);
    }
}

__global__ void k_bscan(const int* __restrict__ bcnt, int* __restrict__ bbase,
                        int* __restrict__ off) {
    __shared__ int buf[512];
    int t = threadIdx.x;
    int v = (t < NBUK) ? bcnt[t] : 0;
    buf[t] = v;
    __syncthreads();
    #pragma unroll
    for (int o = 1; o < 512; o <<= 1) {
        int add = (t >= o) ? buf[t - o] : 0;
        __syncthreads();
        buf[t] += add;
        __syncthreads();
    }
    if (t < NBUK) bbase[t] = buf[t] - v;   // exclusive
    if (t == 0) {
        bbase[NBUK] = NTE;
        off[NN] = NTE;
    }
}

__global__ __launch_bounds__(256) void k_scatter(const int* __restrict__ ei,
                                                 const int* __restrict__ bbase,
                                                 int* __restrict__ bwr,
                                                 int* __restrict__ rec) {
    __shared__ int hist[NBUK];
    __shared__ int cur[NBUK];
    int tid = threadIdx.x;
    for (int b = tid; b < NBUK; b += 256) hist[b] = 0;
    __syncthreads();
    int base = blockIdx.x * EPW;
    #pragma unroll
    for (int r = 0; r < EPW / 256; r++) {
        int idx = base + r * 256 + tid;
        if (idx < NTE) {
            int dst = (idx < NE) ? ei[NE + idx] : (idx - NE);
            atomicAdd(&hist[dst >> 7], 1);
        }
    }
    __syncthreads();
    for (int b = tid; b < NBUK; b += 256) {
        int c = hist[b];
        if (c) cur[b] = bbase[b] + atomicAdd(&bwr[b], c);
    }
    __syncthreads();
    #pragma unroll
    for (int r = 0; r < EPW / 256; r++) {
        int idx = base + r * 256 + tid;
        if (idx < NTE) {
            int src, dst;
            if (idx < NE) { src = ei[idx]; dst = ei[NE + idx]; }
            else          { src = idx - NE; dst = src; }
            int pos = atomicAdd(&cur[dst >> 7], 1);
            rec[pos] = src | ((dst & 127) << 17);
        }
    }
}

// one workgroup per bucket: local 128-scan -> off[], place src into csr window
__global__ __launch_bounds__(256) void k_bfill(const int* __restrict__ bbase,
                                               const int* __restrict__ rec,
                                               int* __restrict__ off,
                                               int* __restrict__ csr) {
    __shared__ int cnt[128];
    __shared__ int scn[128];
    __shared__ int cur[128];
    int b = blockIdx.x, t = threadIdx.x;
    int base = bbase[b];
    int n = bbase[b + 1] - base;
    if (t < 128) cnt[t] = 0;
    __syncthreads();
    for (int i = t; i < n; i += 256) atomicAdd(&cnt[rec[base + i] >> 17], 1);
    __syncthreads();
    if (t < 128) scn[t] = cnt[t];
    __syncthreads();
    #pragma unroll
    for (int o = 1; o < 128; o <<= 1) {
        int add = (t >= o && t < 128) ? scn[t - o] : 0;
        __syncthreads();
        if (t < 128) scn[t] += add;
        __syncthreads();
    }
    if (t < 128) {
        int ex = scn[t] - cnt[t];
        cur[t] = ex;
        int d = b * 128 + t;
        if (d < NN) off[d] = base + ex;
    }
    __syncthreads();
    for (int i = t; i < n; i += 256) {
        int r = rec[base + i];
        int dloc = r >> 17;
        int src = r & 131071;
        int pos = atomicAdd(&cur[dloc], 1);
        csr[base + pos] = src;
    }
}

// ---------------------------------------------------------------------------
// MFMA GEMM  C[M x 128] = A[M x K] * B[K x 128],  A row-major (fp32 or bf16,
// converted to bf16 during LDS staging), Bt = B^T bf16 [128 x K].
// C bf16 out.  BM=128, BN=128, BK=32.
// Fused epilogue: als[row]=dot(Crow,a_s), ald[row]=dot(Crow,a_d)
// ---------------------------------------------------------------------------
template <typename AT>
__global__ __launch_bounds__(256) void k_gemm(const AT* __restrict__ A,
                                              const __bf16* __restrict__ Bt,
                                              __bf16* __restrict__ C,
                                              const float* __restrict__ a_s,
                                              const float* __restrict__ a_d,
                                              float* __restrict__ als,
                                              float* __restrict__ ald,
                                              int M, int K) {
    __shared__ __align__(16) __bf16 As[128][40];   // padded: 80 B rows
    __shared__ __align__(16) __bf16 Bs[128][40];

    int tid = threadIdx.x;
    int rowBase = blockIdx.x * 128;
    int wv = tid >> 6;        // wave 0..3
    int lane = tid & 63;
    int g = lane >> 4;        // k-slice selector (0..3)
    int c = lane & 15;        // col-in-tile / row-in-tile selector

    f32x4 acc[2][8];
    #pragma unroll
    for (int mi = 0; mi < 2; mi++)
        #pragma unroll
        for (int ni = 0; ni < 8; ni++) acc[mi][ni] = (f32x4){0.f, 0.f, 0.f, 0.f};

    for (int k0 = 0; k0 < K; k0 += 32) {
        __syncthreads();
        // stage A tile (convert to bf16 if AT==float)
        #pragma unroll
        for (int rep = 0; rep < 2; rep++) {
            int ch = tid + rep * 256;
            int r = ch >> 2, q = ch & 3;
            int row = rowBase + r;
            if constexpr (sizeof(AT) == 2) {
                float4 v = {0.f, 0.f, 0.f, 0.f};
                if (row < M) v = *(const float4*)((const __bf16*)A + (size_t)row * K + k0 + q * 8);
                *(float4*)&As[r][q * 8] = v;
            } else {
                float vv[8] = {0.f, 0.f, 0.f, 0.f, 0.f, 0.f, 0.f, 0.f};
                if (row < M) {
                    const float* Ap = (const float*)A + (size_t)row * K + k0 + q * 8;
                    float4 v0 = *(const float4*)Ap;
                    float4 v1 = *(const float4*)(Ap + 4);
                    vv[0] = v0.x; vv[1] = v0.y; vv[2] = v0.z; vv[3] = v0.w;
                    vv[4] = v1.x; vv[5] = v1.y; vv[6] = v1.z; vv[7] = v1.w;
                }
                V16 o;
                #pragma unroll
                for (int t = 0; t < 8; t++) o.h[t] = (__bf16)vv[t];
                *(float4*)&As[r][q * 8] = o.f4;
            }
        }
        // stage Bt tile
        #pragma unroll
        for (int rep = 0; rep < 2; rep++) {
            int ch = tid + rep * 256;
            int r = ch >> 2, q = ch & 3;
            float4 v = *(const float4*)(Bt + (size_t)r * K + k0 + q * 8);
            *(float4*)&Bs[r][q * 8] = v;
        }
        __syncthreads();

        bf16x8 a0 = *(const bf16x8*)&As[wv * 32 + c][g * 8];
        bf16x8 a1 = *(const bf16x8*)&As[wv * 32 + 16 + c][g * 8];
        #pragma unroll
        for (int ni = 0; ni < 8; ni++) {
            bf16x8 b = *(const bf16x8*)&Bs[ni * 16 + c][g * 8];
            acc[0][ni] = __builtin_amdgcn_mfma_f32_16x16x32_bf16(a0, b, acc[0][ni], 0, 0, 0);
            acc[1][ni] = __builtin_amdgcn_mfma_f32_16x16x32_bf16(a1, b, acc[1][ni], 0, 0, 0);
        }
    }

    float asv[8], adv[8];
    #pragma unroll
    for (int ni = 0; ni < 8; ni++) {
        asv[ni] = a_s[ni * 16 + c];
        adv[ni] = a_d[ni * 16 + c];
    }
    #pragma unroll
    for (int mi = 0; mi < 2; mi++) {
        int rb = rowBase + wv * 32 + mi * 16 + g * 4;
        #pragma unroll
        for (int i = 0; i < 4; i++) {
            int row = rb + i;
            float s = 0.f, dd = 0.f;
            #pragma unroll
            for (int ni = 0; ni < 8; ni++) {
                float v = acc[mi][ni][i];
                s = fmaf(v, asv[ni], s);
                dd = fmaf(v, adv[ni], dd);
            }
            #pragma unroll
            for (int o = 1; o <= 8; o <<= 1) {
                s += __shfl_xor(s, o);
                dd += __shfl_xor(dd, o);
            }
            if (row < M) {
                #pragma unroll
                for (int ni = 0; ni < 8; ni++)
                    C[(size_t)row * HID + ni * 16 + c] = (__bf16)acc[mi][ni][i];
                if (c == 0) {
                    als[row] = s;
                    ald[row] = dd;
                }
            }
        }
    }
}

// ---------------------------------------------------------------------------
// fused softmax + weighted gather: one wave per dst node.
// Phase 1 (unchanged): lane j handles edge e0+j; cf stashed in per-wave LDS.
// Phase 2 (NEW): 8-lane edge groups -> 8 edges in flight; each lane covers
//   16 dims (two float4 loads, 32 B). Serial depth deg/8 ~= 2.
// ---------------------------------------------------------------------------
__global__ __launch_bounds__(256) void k_attn(const __bf16* __restrict__ h,
                                              const float* __restrict__ als,
                                              const float* __restrict__ ald,
                                              const int* __restrict__ off,
                                              const int* __restrict__ csr,
                                              const float* __restrict__ bias,
                                              __bf16* __restrict__ yout,
                                              int do_relu) {
    __shared__ int s_src[4][64];
    __shared__ float s_cf[4][64];
    int gt = blockIdx.x * blockDim.x + threadIdx.x;
    int d = gt >> 6;
    int lane = gt & 63;
    if (d >= NN) return;
    int wv = threadIdx.x >> 6;   // wave within block
    int grp = lane >> 3;         // edge slot 0..7
    int c = lane & 7;            // dim block (16 dims: c*16 .. c*16+15)

    int e0 = off[d], e1 = off[d + 1];
    int deg = e1 - e0;
    float ald_d = ald[d];
    float acc[16];
    #pragma unroll
    for (int t = 0; t < 16; t++) acc[t] = 0.f;

    if (deg <= 64) {
        // ---- phase 1: softmax ----
        int s = 0;
        float e = -INFINITY;
        if (lane < deg) {
            s = csr[e0 + lane];
            float t = als[s] + ald_d;
            e = (t > 0.0f) ? t : NEG_SLOPE * t;
        }
        float mx = e;
        #pragma unroll
        for (int o = 32; o > 0; o >>= 1) mx = fmaxf(mx, __shfl_xor(mx, o));
        float p = (lane < deg) ? __expf(e - mx) : 0.0f;
        float z = p;
        #pragma unroll
        for (int o = 32; o > 0; o >>= 1) z += __shfl_xor(z, o);
        float inv_z = 1.0f / z;          // self loop guarantees z > 0
        s_src[wv][lane] = s;
        s_cf[wv][lane] = p * inv_z;

        // ---- phase 2: gather, 8 edges in flight ----
        #pragma unroll 2
        for (int k = grp; k < deg; k += 8) {
            int ss = s_src[wv][k];       // uniform within 8-lane group
            float cf = s_cf[wv][k];
            const __bf16* hp = h + (size_t)ss * HID + c * 16;
            V16 v0, v1;
            v0.f4 = *(const float4*)hp;
            v1.f4 = *(const float4*)(hp + 8);
            #pragma unroll
            for (int t = 0; t < 8; t++) {
                acc[t] = fmaf(cf, (float)v0.h[t], acc[t]);
                acc[8 + t] = fmaf(cf, (float)v1.h[t], acc[8 + t]);
            }
        }
    } else {
        // ---- rare slow path: strided two-pass + per-edge recompute ----
        float mx = -INFINITY;
        for (int j = e0 + lane; j < e1; j += 64) {
            float t = als[csr[j]] + ald_d;
            t = (t > 0.0f) ? t : NEG_SLOPE * t;
            mx = fmaxf(mx, t);
        }
        #pragma unroll
        for (int o = 32; o > 0; o >>= 1) mx = fmaxf(mx, __shfl_xor(mx, o));
        float z = 0.0f;
        for (int j = e0 + lane; j < e1; j += 64) {
            float t = als[csr[j]] + ald_d;
            t = (t > 0.0f) ? t : NEG_SLOPE * t;
            z += __expf(t - mx);
        }
        #pragma unroll
        for (int o = 32; o > 0; o >>= 1) z += __shfl_xor(z, o);
        float inv_z = 1.0f / z;
        for (int k = grp; k < deg; k += 8) {
            int ss = csr[e0 + k];
            float t = als[ss] + ald_d;
            t = (t > 0.0f) ? t : NEG_SLOPE * t;
            float cf = __expf(t - mx) * inv_z;
            const __bf16* hp = h + (size_t)ss * HID + c * 16;
            V16 v0, v1;
            v0.f4 = *(const float4*)hp;
            v1.f4 = *(const float4*)(hp + 8);
            #pragma unroll
            for (int t2 = 0; t2 < 8; t2++) {
                acc[t2] = fmaf(cf, (float)v0.h[t2], acc[t2]);
                acc[8 + t2] = fmaf(cf, (float)v1.h[t2], acc[8 + t2]);
            }
        }
    }

    // combine the 8 edge-groups
    #pragma unroll
    for (int t = 0; t < 16; t++) {
        acc[t] += __shfl_xor(acc[t], 8);
        acc[t] += __shfl_xor(acc[t], 16);
        acc[t] += __shfl_xor(acc[t], 32);
    }

    if (grp == 0) {
        // lane c (0..7) owns dims c*16 .. c*16+15
        float4 b0 = *(const float4*)(bias + c * 16);
        float4 b1 = *(const float4*)(bias + c * 16 + 4);
        float4 b2 = *(const float4*)(bias + c * 16 + 8);
        float4 b3 = *(const float4*)(bias + c * 16 + 12);
        acc[0] += b0.x;  acc[1] += b0.y;  acc[2] += b0.z;  acc[3] += b0.w;
        acc[4] += b1.x;  acc[5] += b1.y;  acc[6] += b1.z;  acc[7] += b1.w;
        acc[8] += b2.x;  acc[9] += b2.y;  acc[10] += b2.z; acc[11] += b2.w;
        acc[12] += b3.x; acc[13] += b3.y; acc[14] += b3.z; acc[15] += b3.w;
        if (do_relu) {
            #pragma unroll
            for (int t = 0; t < 16; t++) acc[t] = fmaxf(acc[t], 0.0f);
        }
        V16 o0, o1;
        #pragma unroll
        for (int t = 0; t < 8; t++) {
            o0.h[t] = (__bf16)acc[t];
            o1.h[t] = (__bf16)acc[8 + t];
        }
        __bf16* yp = yout + (size_t)d * HID + c * 16;
        *(float4*)yp = o0.f4;
        *(float4*)(yp + 8) = o1.f4;
    }
}

// ---------------------------------------------------------------------------
// global mean pool: batch is sorted; per-block run-length accumulation.
// emb is bf16; accumulate fp32.
// ---------------------------------------------------------------------------
__global__ void k_pool(const __bf16* __restrict__ emb, const int* __restrict__ batch,
                       float* __restrict__ sums) {
    int t = threadIdx.x;          // dim
    int base = blockIdx.x * 128;
    int end = base + 128;
    if (end > NN) end = NN;
    float acc = 0.0f;
    int g_cur = -1;
    for (int n = base; n < end; ++n) {
        int g = batch[n];
        if (g != g_cur) {
            if (g_cur >= 0) atomicAdd(&sums[g_cur * HID + t], acc);
            acc = 0.0f;
            g_cur = g;
        }
        acc += (float)emb[(size_t)n * HID + t];
    }
    if (g_cur >= 0) atomicAdd(&sums[g_cur * HID + t], acc);
}

// counts via binary search on the sorted batch array
__global__ void k_div(const float* __restrict__ sums, const int* __restrict__ batch,
                      float* __restrict__ out) {
    int i = blockIdx.x * blockDim.x + threadIdx.x;
    if (i >= NG * HID) return;
    int g = i >> 7;
    int lo = 0, hi = NN;
    while (lo < hi) { int mid = (lo + hi) >> 1; if (batch[mid] < g) lo = mid + 1; else hi = mid; }
    int lo2 = lo, hi2 = NN;
    while (lo2 < hi2) { int mid = (lo2 + hi2) >> 1; if (batch[mid] < g + 1) lo2 = mid + 1; else hi2 = mid; }
    int c = lo2 - lo;
    out[i] = sums[i] / (float)(c > 1 ? c : 1);
}

// ---------------------------------------------------------------------------
extern "C" void kernel_launch(void* const* d_in, const int* in_sizes, int n_in,
                              void* d_out, int out_size, void* d_ws, size_t ws_size,
                              hipStream_t stream) {
    const float* x     = (const float*)d_in[0];   // [50000,256]
    const int*   ei    = (const int*)d_in[1];     // [2,800000]
    const int*   batch = (const int*)d_in[2];     // [50000]
    const float* W[3]  = {(const float*)d_in[3], (const float*)d_in[7], (const float*)d_in[11]};
    const float* AS[3] = {(const float*)d_in[4], (const float*)d_in[8], (const float*)d_in[12]};
    const float* AD[3] = {(const float*)d_in[5], (const float*)d_in[9], (const float*)d_in[13]};
    const float* BI[3] = {(const float*)d_in[6], (const float*)d_in[10], (const float*)d_in[14]};
    float* out = (float*)d_out;

    // workspace layout (~31 MB)
    char* ws = (char*)d_ws;
    size_t o = 0;
    auto alloc = [&](size_t bytes) {
        void* p = ws + o;
        o = (o + bytes + 255) & ~(size_t)255;
        return p;
    };
    __bf16* hb  = (__bf16*)alloc((size_t)NN * HID * 2);   // GEMM output (12.8 MB)
    __bf16* yb  = (__bf16*)alloc((size_t)NN * HID * 2);   // layer output bf16 (12.8 MB)
    __bf16* Wt0 = (__bf16*)alloc((size_t)256 * HID * 2);
    __bf16* Wt1 = (__bf16*)alloc((size_t)HID * HID * 2);
    __bf16* Wt2 = (__bf16*)alloc((size_t)HID * HID * 2);
    float* als  = (float*)alloc(NN * 4);
    float* ald  = (float*)alloc(NN * 4);
    int* off    = (int*)alloc((NN + 1) * 4);
    int* bcnt   = (int*)alloc((NBUK + 1) * 4);
    int* bwr    = (int*)alloc((NBUK + 1) * 4);
    int* bbase  = (int*)alloc((NBUK + 1) * 4);
    int* rec    = (int*)alloc((size_t)NTE * 4);
    int* csr    = (int*)alloc((size_t)NTE * 4);
    float* sums = (float*)alloc(NG * HID * 4);
    (void)ws_size; (void)in_sizes; (void)n_in; (void)out_size;

    // ---- prep: zero init + weight transposes (one dispatch) ----
    k_prep<<<(256 * HID + 2 * HID * HID + 255) / 256, 256, 0, stream>>>(
        bcnt, bwr, sums, W[0], W[1], W[2], Wt0, Wt1, Wt2);

    // ---- bucketed CSR build ----
    k_bcnt<<<NWG_E, 256, 0, stream>>>(ei, bcnt);
    k_bscan<<<1, 512, 0, stream>>>(bcnt, bbase, off);
    k_scatter<<<NWG_E, 256, 0, stream>>>(ei, bbase, bwr, rec);
    k_bfill<<<NBUK, 256, 0, stream>>>(bbase, rec, off, csr);

    const int gemm_grid = (NN + 127) / 128;      // 391
    const int wave_grid = (NN * 64 + 255) / 256; // 12500

    // ---- layer 0 (K=256, A=fp32 x, relu) ----
    k_gemm<float><<<gemm_grid, 256, 0, stream>>>(x, Wt0, hb, AS[0], AD[0], als, ald, NN, 256);
    k_attn<<<wave_grid, 256, 0, stream>>>(hb, als, ald, off, csr, BI[0], yb, 1);

    // ---- layer 1 (K=128, relu) ----
    k_gemm<__bf16><<<gemm_grid, 256, 0, stream>>>(yb, Wt1, hb, AS[1], AD[1], als, ald, NN, HID);
    k_attn<<<wave_grid, 256, 0, stream>>>(hb, als, ald, off, csr, BI[1], yb, 1);

    // ---- layer 2 (K=128, no relu) ----
    k_gemm<__bf16><<<gemm_grid, 256, 0, stream>>>(yb, Wt2, hb, AS[2], AD[2], als, ald, NN, HID);
    k_attn<<<wave_grid, 256, 0, stream>>>(hb, als, ald, off, csr, BI[2], yb, 0);

    // ---- global mean pool ----
    k_pool<<<(NN + 127) / 128, 128, 0, stream>>>(yb, batch, sums);
    k_div<<<(NG * HID + 255) / 256, 256, 0, stream>>>(sums, batch, out);
}

// Round 9
// 344.599 us; speedup vs baseline: 1.0531x; 1.0531x over previous
//
#include <hip/hip_runtime.h>
#include <math.h>

// Problem constants (fixed by the reference setup)
#define NN 50000          // nodes
#define NE 800000         // edges (before self loops)
#define NTE (NE + NN)     // edges incl self loops
#define NG 16             // graphs
#define HID 128           // hidden/out dim (all layers out=128)
#define NEG_SLOPE 0.2f

#define NBUK 391          // ceil(NN/128) buckets of 128 dst nodes
#define EPW 4096          // edges per workgroup in bucket count/scatter
#define NWG_E ((NTE + EPW - 1) / EPW)   // 208

typedef __attribute__((ext_vector_type(8))) __bf16 bf16x8;
typedef __attribute__((ext_vector_type(4))) float f32x4;

union V16 {
    float4 f4;
    uint4 u4;
    bf16x8 b8;
    __bf16 h[8];
};

// ---------------------------------------------------------------------------
// prep: zero bcnt/bwr/sums + all three weight transposes, one dispatch.
// W [K][128] fp32 -> Wt [128][K] bf16
// ---------------------------------------------------------------------------
__global__ void k_prep(int* __restrict__ bcnt, int* __restrict__ bwr,
                       float* __restrict__ sums,
                       const float* __restrict__ W0, const float* __restrict__ W1,
                       const float* __restrict__ W2, __bf16* __restrict__ Wt0,
                       __bf16* __restrict__ Wt1, __bf16* __restrict__ Wt2) {
    int t = blockIdx.x * blockDim.x + threadIdx.x;
    if (t <= NBUK) {
        bcnt[t] = 0;
        bwr[t] = 0;
    }
    if (t < NG * HID) sums[t] = 0.0f;
    if (t < 256 * HID) {
        int k = t >> 7, n = t & 127;
        Wt0[(size_t)n * 256 + k] = (__bf16)W0[t];
    } else if (t < 256 * HID + HID * HID) {
        int u = t - 256 * HID;
        int k = u >> 7, n = u & 127;
        Wt1[(size_t)n * HID + k] = (__bf16)W1[u];
    } else if (t < 256 * HID + 2 * HID * HID) {
        int u = t - 256 * HID - HID * HID;
        int k = u >> 7, n = u & 127;
        Wt2[(size_t)n * HID + k] = (__bf16)W2[u];
    }
}

// ---------------------------------------------------------------------------
// Bucketed CSR build.  rec[] holds src | (dst&127)<<17, grouped by bucket.
// ---------------------------------------------------------------------------
__global__ __launch_bounds__(256) void k_bcnt(const int* __restrict__ ei,
                                              int* __restrict__ bcnt) {
    __shared__ int hist[NBUK];
    int tid = threadIdx.x;
    for (int b = tid; b < NBUK; b += 256) hist[b] = 0;
    __syncthreads();
    int base = blockIdx.x * EPW;
    #pragma unroll
    for (int r = 0; r < EPW / 256; r++) {
        int idx = base + r * 256 + tid;
        if (idx < NTE) {
            int dst = (idx < NE) ? ei[NE + idx] : (idx - NE);
            atomicAdd(&hist[dst >> 7], 1);
        }
    }
    __syncthreads();
    for (int b = tid; b < NBUK; b += 256) {
        int c = hist[b];
        if (c) atomicAdd(&bcnt[b], c);
    }
}

__global__ void k_bscan(const int* __restrict__ bcnt, int* __restrict__ bbase,
                        int* __restrict__ off) {
    __shared__ int buf[512];
    int t = threadIdx.x;
    int v = (t < NBUK) ? bcnt[t] : 0;
    buf[t] = v;
    __syncthreads();
    #pragma unroll
    for (int o = 1; o < 512; o <<= 1) {
        int add = (t >= o) ? buf[t - o] : 0;
        __syncthreads();
        buf[t] += add;
        __syncthreads();
    }
    if (t < NBUK) bbase[t] = buf[t] - v;   // exclusive
    if (t == 0) {
        bbase[NBUK] = NTE;
        off[NN] = NTE;
    }
}

__global__ __launch_bounds__(256) void k_scatter(const int* __restrict__ ei,
                                                 const int* __restrict__ bbase,
                                                 int* __restrict__ bwr,
                                                 int* __restrict__ rec) {
    __shared__ int hist[NBUK];
    __shared__ int cur[NBUK];
    int tid = threadIdx.x;
    for (int b = tid; b < NBUK; b += 256) hist[b] = 0;
    __syncthreads();
    int base = blockIdx.x * EPW;
    #pragma unroll
    for (int r = 0; r < EPW / 256; r++) {
        int idx = base + r * 256 + tid;
        if (idx < NTE) {
            int dst = (idx < NE) ? ei[NE + idx] : (idx - NE);
            atomicAdd(&hist[dst >> 7], 1);
        }
    }
    __syncthreads();
    for (int b = tid; b < NBUK; b += 256) {
        int c = hist[b];
        if (c) cur[b] = bbase[b] + atomicAdd(&bwr[b], c);
    }
    __syncthreads();
    #pragma unroll
    for (int r = 0; r < EPW / 256; r++) {
        int idx = base + r * 256 + tid;
        if (idx < NTE) {
            int src, dst;
            if (idx < NE) { src = ei[idx]; dst = ei[NE + idx]; }
            else          { src = idx - NE; dst = src; }
            int pos = atomicAdd(&cur[dst >> 7], 1);
            rec[pos] = src | ((dst & 127) << 17);
        }
    }
}

// one workgroup per bucket: local 128-scan -> off[], place src into csr window
__global__ __launch_bounds__(256) void k_bfill(const int* __restrict__ bbase,
                                               const int* __restrict__ rec,
                                               int* __restrict__ off,
                                               int* __restrict__ csr) {
    __shared__ int cnt[128];
    __shared__ int scn[128];
    __shared__ int cur[128];
    int b = blockIdx.x, t = threadIdx.x;
    int base = bbase[b];
    int n = bbase[b + 1] - base;
    if (t < 128) cnt[t] = 0;
    __syncthreads();
    for (int i = t; i < n; i += 256) atomicAdd(&cnt[rec[base + i] >> 17], 1);
    __syncthreads();
    if (t < 128) scn[t] = cnt[t];
    __syncthreads();
    #pragma unroll
    for (int o = 1; o < 128; o <<= 1) {
        int add = (t >= o && t < 128) ? scn[t - o] : 0;
        __syncthreads();
        if (t < 128) scn[t] += add;
        __syncthreads();
    }
    if (t < 128) {
        int ex = scn[t] - cnt[t];
        cur[t] = ex;
        int d = b * 128 + t;
        if (d < NN) off[d] = base + ex;
    }
    __syncthreads();
    for (int i = t; i < n; i += 256) {
        int r = rec[base + i];
        int dloc = r >> 17;
        int src = r & 131071;
        int pos = atomicAdd(&cur[dloc], 1);
        csr[base + pos] = src;
    }
}

// ---------------------------------------------------------------------------
// MFMA GEMM  C[M x 128] = A[M x K] * B[K x 128],  A row-major (fp32 or bf16,
// converted to bf16 during LDS staging), Bt = B^T bf16 [128 x K].
// C bf16 out.  BM=128, BN=128, BK=32.
// Fused epilogue: als[row]=dot(Crow,a_s), ald[row]=dot(Crow,a_d)
// ---------------------------------------------------------------------------
template <typename AT>
__global__ __launch_bounds__(256) void k_gemm(const AT* __restrict__ A,
                                              const __bf16* __restrict__ Bt,
                                              __bf16* __restrict__ C,
                                              const float* __restrict__ a_s,
                                              const float* __restrict__ a_d,
                                              float* __restrict__ als,
                                              float* __restrict__ ald,
                                              int M, int K) {
    __shared__ __align__(16) __bf16 As[128][40];   // padded: 80 B rows
    __shared__ __align__(16) __bf16 Bs[128][40];

    int tid = threadIdx.x;
    int rowBase = blockIdx.x * 128;
    int wv = tid >> 6;        // wave 0..3
    int lane = tid & 63;
    int g = lane >> 4;        // k-slice selector (0..3)
    int c = lane & 15;        // col-in-tile / row-in-tile selector

    f32x4 acc[2][8];
    #pragma unroll
    for (int mi = 0; mi < 2; mi++)
        #pragma unroll
        for (int ni = 0; ni < 8; ni++) acc[mi][ni] = (f32x4){0.f, 0.f, 0.f, 0.f};

    for (int k0 = 0; k0 < K; k0 += 32) {
        __syncthreads();
        // stage A tile (convert to bf16 if AT==float)
        #pragma unroll
        for (int rep = 0; rep < 2; rep++) {
            int ch = tid + rep * 256;
            int r = ch >> 2, q = ch & 3;
            int row = rowBase + r;
            if constexpr (sizeof(AT) == 2) {
                float4 v = {0.f, 0.f, 0.f, 0.f};
                if (row < M) v = *(const float4*)((const __bf16*)A + (size_t)row * K + k0 + q * 8);
                *(float4*)&As[r][q * 8] = v;
            } else {
                float vv[8] = {0.f, 0.f, 0.f, 0.f, 0.f, 0.f, 0.f, 0.f};
                if (row < M) {
                    const float* Ap = (const float*)A + (size_t)row * K + k0 + q * 8;
                    float4 v0 = *(const float4*)Ap;
                    float4 v1 = *(const float4*)(Ap + 4);
                    vv[0] = v0.x; vv[1] = v0.y; vv[2] = v0.z; vv[3] = v0.w;
                    vv[4] = v1.x; vv[5] = v1.y; vv[6] = v1.z; vv[7] = v1.w;
                }
                V16 o;
                #pragma unroll
                for (int t = 0; t < 8; t++) o.h[t] = (__bf16)vv[t];
                *(float4*)&As[r][q * 8] = o.f4;
            }
        }
        // stage Bt tile
        #pragma unroll
        for (int rep = 0; rep < 2; rep++) {
            int ch = tid + rep * 256;
            int r = ch >> 2, q = ch & 3;
            float4 v = *(const float4*)(Bt + (size_t)r * K + k0 + q * 8);
            *(float4*)&Bs[r][q * 8] = v;
        }
        __syncthreads();

        bf16x8 a0 = *(const bf16x8*)&As[wv * 32 + c][g * 8];
        bf16x8 a1 = *(const bf16x8*)&As[wv * 32 + 16 + c][g * 8];
        #pragma unroll
        for (int ni = 0; ni < 8; ni++) {
            bf16x8 b = *(const bf16x8*)&Bs[ni * 16 + c][g * 8];
            acc[0][ni] = __builtin_amdgcn_mfma_f32_16x16x32_bf16(a0, b, acc[0][ni], 0, 0, 0);
            acc[1][ni] = __builtin_amdgcn_mfma_f32_16x16x32_bf16(a1, b, acc[1][ni], 0, 0, 0);
        }
    }

    float asv[8], adv[8];
    #pragma unroll
    for (int ni = 0; ni < 8; ni++) {
        asv[ni] = a_s[ni * 16 + c];
        adv[ni] = a_d[ni * 16 + c];
    }
    #pragma unroll
    for (int mi = 0; mi < 2; mi++) {
        int rb = rowBase + wv * 32 + mi * 16 + g * 4;
        #pragma unroll
        for (int i = 0; i < 4; i++) {
            int row = rb + i;
            float s = 0.f, dd = 0.f;
            #pragma unroll
            for (int ni = 0; ni < 8; ni++) {
                float v = acc[mi][ni][i];
                s = fmaf(v, asv[ni], s);
                dd = fmaf(v, adv[ni], dd);
            }
            #pragma unroll
            for (int o = 1; o <= 8; o <<= 1) {
                s += __shfl_xor(s, o);
                dd += __shfl_xor(dd, o);
            }
            if (row < M) {
                #pragma unroll
                for (int ni = 0; ni < 8; ni++)
                    C[(size_t)row * HID + ni * 16 + c] = (__bf16)acc[mi][ni][i];
                if (c == 0) {
                    als[row] = s;
                    ald[row] = dd;
                }
            }
        }
    }
}

// ---------------------------------------------------------------------------
// fused softmax + weighted gather: one wave per dst node.
// Phase 1: lane j handles edge e0+j; (src, cf-bits) packed into one LDS int2.
// Phase 2: 16-lane edge groups (4 edges in flight), one float4 (8 bf16) per
//   lane per edge; bf16->f32 via exact bit ops; adjacent-pair fmas.
//   Arithmetic identical to round 7 (same dim-wise chains) -> bitwise-equal y.
// ---------------------------------------------------------------------------
__global__ __launch_bounds__(256) void k_attn(const __bf16* __restrict__ h,
                                              const float* __restrict__ als,
                                              const float* __restrict__ ald,
                                              const int* __restrict__ off,
                                              const int* __restrict__ csr,
                                              const float* __restrict__ bias,
                                              __bf16* __restrict__ yout,
                                              int do_relu) {
    __shared__ int2 s_e[4][64];   // (src, cf bits) per wave
    int gt = blockIdx.x * blockDim.x + threadIdx.x;
    int d = gt >> 6;
    int lane = gt & 63;
    if (d >= NN) return;
    int wv = threadIdx.x >> 6;   // wave within block
    int grp = lane >> 4;         // edge slot 0..3
    int c = lane & 15;           // dim block (8 dims: c*8 .. c*8+7)

    int e0 = off[d], e1 = off[d + 1];
    int deg = e1 - e0;
    float ald_d = ald[d];
    float acc[8] = {0.f, 0.f, 0.f, 0.f, 0.f, 0.f, 0.f, 0.f};

    if (deg <= 64) {
        // ---- phase 1: softmax ----
        int s = 0;
        float e = -INFINITY;
        if (lane < deg) {
            s = csr[e0 + lane];
            float t = als[s] + ald_d;
            e = (t > 0.0f) ? t : NEG_SLOPE * t;
        }
        float mx = e;
        #pragma unroll
        for (int o = 32; o > 0; o >>= 1) mx = fmaxf(mx, __shfl_xor(mx, o));
        float p = (lane < deg) ? __expf(e - mx) : 0.0f;
        float z = p;
        #pragma unroll
        for (int o = 32; o > 0; o >>= 1) z += __shfl_xor(z, o);
        float inv_z = 1.0f / z;          // self loop guarantees z > 0
        s_e[wv][lane] = make_int2(s, __float_as_int(p * inv_z));

        // ---- phase 2: gather, 4 edges in flight ----
        #pragma unroll 4
        for (int k = grp; k < deg; k += 4) {
            int2 pr = s_e[wv][k];        // uniform within 16-lane group
            int ss = pr.x;
            float cf = __int_as_float(pr.y);
            V16 v;
            v.f4 = *(const float4*)(h + (size_t)ss * HID + c * 8);
            #pragma unroll
            for (int i = 0; i < 4; i++) {
                unsigned int u = (&v.u4.x)[i];
                float lo = __uint_as_float(u << 16);
                float hi = __uint_as_float(u & 0xffff0000u);
                acc[2 * i]     = fmaf(cf, lo, acc[2 * i]);
                acc[2 * i + 1] = fmaf(cf, hi, acc[2 * i + 1]);
            }
        }
    } else {
        // ---- rare slow path: strided two-pass + per-edge recompute ----
        float mx = -INFINITY;
        for (int j = e0 + lane; j < e1; j += 64) {
            float t = als[csr[j]] + ald_d;
            t = (t > 0.0f) ? t : NEG_SLOPE * t;
            mx = fmaxf(mx, t);
        }
        #pragma unroll
        for (int o = 32; o > 0; o >>= 1) mx = fmaxf(mx, __shfl_xor(mx, o));
        float z = 0.0f;
        for (int j = e0 + lane; j < e1; j += 64) {
            float t = als[csr[j]] + ald_d;
            t = (t > 0.0f) ? t : NEG_SLOPE * t;
            z += __expf(t - mx);
        }
        #pragma unroll
        for (int o = 32; o > 0; o >>= 1) z += __shfl_xor(z, o);
        float inv_z = 1.0f / z;
        for (int k = grp; k < deg; k += 4) {
            int ss = csr[e0 + k];
            float t = als[ss] + ald_d;
            t = (t > 0.0f) ? t : NEG_SLOPE * t;
            float cf = __expf(t - mx) * inv_z;
            V16 v;
            v.f4 = *(const float4*)(h + (size_t)ss * HID + c * 8);
            #pragma unroll
            for (int i = 0; i < 4; i++) {
                unsigned int u = (&v.u4.x)[i];
                float lo = __uint_as_float(u << 16);
                float hi = __uint_as_float(u & 0xffff0000u);
                acc[2 * i]     = fmaf(cf, lo, acc[2 * i]);
                acc[2 * i + 1] = fmaf(cf, hi, acc[2 * i + 1]);
            }
        }
    }

    // combine the 4 edge-groups
    #pragma unroll
    for (int t = 0; t < 8; t++) {
        acc[t] += __shfl_xor(acc[t], 16);
        acc[t] += __shfl_xor(acc[t], 32);
    }

    if (grp == 0) {
        float4 b0 = *(const float4*)(bias + c * 8);
        float4 b1 = *(const float4*)(bias + c * 8 + 4);
        acc[0] += b0.x; acc[1] += b0.y; acc[2] += b0.z; acc[3] += b0.w;
        acc[4] += b1.x; acc[5] += b1.y; acc[6] += b1.z; acc[7] += b1.w;
        if (do_relu) {
            #pragma unroll
            for (int t = 0; t < 8; t++) acc[t] = fmaxf(acc[t], 0.0f);
        }
        V16 o;
        #pragma unroll
        for (int t = 0; t < 8; t++) o.h[t] = (__bf16)acc[t];
        *(float4*)(yout + (size_t)d * HID + c * 8) = o.f4;
    }
}

// ---------------------------------------------------------------------------
// global mean pool: batch is sorted; per-block run-length accumulation.
// emb is bf16; accumulate fp32.
// ---------------------------------------------------------------------------
__global__ void k_pool(const __bf16* __restrict__ emb, const int* __restrict__ batch,
                       float* __restrict__ sums) {
    int t = threadIdx.x;          // dim
    int base = blockIdx.x * 128;
    int end = base + 128;
    if (end > NN) end = NN;
    float acc = 0.0f;
    int g_cur = -1;
    for (int n = base; n < end; ++n) {
        int g = batch[n];
        if (g != g_cur) {
            if (g_cur >= 0) atomicAdd(&sums[g_cur * HID + t], acc);
            acc = 0.0f;
            g_cur = g;
        }
        acc += (float)emb[(size_t)n * HID + t];
    }
    if (g_cur >= 0) atomicAdd(&sums[g_cur * HID + t], acc);
}

// counts via binary search on the sorted batch array
__global__ void k_div(const float* __restrict__ sums, const int* __restrict__ batch,
                      float* __restrict__ out) {
    int i = blockIdx.x * blockDim.x + threadIdx.x;
    if (i >= NG * HID) return;
    int g = i >> 7;
    int lo = 0, hi = NN;
    while (lo < hi) { int mid = (lo + hi) >> 1; if (batch[mid] < g) lo = mid + 1; else hi = mid; }
    int lo2 = lo, hi2 = NN;
    while (lo2 < hi2) { int mid = (lo2 + hi2) >> 1; if (batch[mid] < g + 1) lo2 = mid + 1; else hi2 = mid; }
    int c = lo2 - lo;
    out[i] = sums[i] / (float)(c > 1 ? c : 1);
}

// ---------------------------------------------------------------------------
extern "C" void kernel_launch(void* const* d_in, const int* in_sizes, int n_in,
                              void* d_out, int out_size, void* d_ws, size_t ws_size,
                              hipStream_t stream) {
    const float* x     = (const float*)d_in[0];   // [50000,256]
    const int*   ei    = (const int*)d_in[1];     // [2,800000]
    const int*   batch = (const int*)d_in[2];     // [50000]
    const float* W[3]  = {(const float*)d_in[3], (const float*)d_in[7], (const float*)d_in[11]};
    const float* AS[3] = {(const float*)d_in[4], (const float*)d_in[8], (const float*)d_in[12]};
    const float* AD[3] = {(const float*)d_in[5], (const float*)d_in[9], (const float*)d_in[13]};
    const float* BI[3] = {(const float*)d_in[6], (const float*)d_in[10], (const float*)d_in[14]};
    float* out = (float*)d_out;

    // workspace layout (~31 MB)
    char* ws = (char*)d_ws;
    size_t o = 0;
    auto alloc = [&](size_t bytes) {
        void* p = ws + o;
        o = (o + bytes + 255) & ~(size_t)255;
        return p;
    };
    __bf16* hb  = (__bf16*)alloc((size_t)NN * HID * 2);   // GEMM output (12.8 MB)
    __bf16* yb  = (__bf16*)alloc((size_t)NN * HID * 2);   // layer output bf16 (12.8 MB)
    __bf16* Wt0 = (__bf16*)alloc((size_t)256 * HID * 2);
    __bf16* Wt1 = (__bf16*)alloc((size_t)HID * HID * 2);
    __bf16* Wt2 = (__bf16*)alloc((size_t)HID * HID * 2);
    float* als  = (float*)alloc(NN * 4);
    float* ald  = (float*)alloc(NN * 4);
    int* off    = (int*)alloc((NN + 1) * 4);
    int* bcnt   = (int*)alloc((NBUK + 1) * 4);
    int* bwr    = (int*)alloc((NBUK + 1) * 4);
    int* bbase  = (int*)alloc((NBUK + 1) * 4);
    int* rec    = (int*)alloc((size_t)NTE * 4);
    int* csr    = (int*)alloc((size_t)NTE * 4);
    float* sums = (float*)alloc(NG * HID * 4);
    (void)ws_size; (void)in_sizes; (void)n_in; (void)out_size;

    // ---- prep: zero init + weight transposes (one dispatch) ----
    k_prep<<<(256 * HID + 2 * HID * HID + 255) / 256, 256, 0, stream>>>(
        bcnt, bwr, sums, W[0], W[1], W[2], Wt0, Wt1, Wt2);

    // ---- bucketed CSR build ----
    k_bcnt<<<NWG_E, 256, 0, stream>>>(ei, bcnt);
    k_bscan<<<1, 512, 0, stream>>>(bcnt, bbase, off);
    k_scatter<<<NWG_E, 256, 0, stream>>>(ei, bbase, bwr, rec);
    k_bfill<<<NBUK, 256, 0, stream>>>(bbase, rec, off, csr);

    const int gemm_grid = (NN + 127) / 128;      // 391
    const int wave_grid = (NN * 64 + 255) / 256; // 12500

    // ---- layer 0 (K=256, A=fp32 x, relu) ----
    k_gemm<float><<<gemm_grid, 256, 0, stream>>>(x, Wt0, hb, AS[0], AD[0], als, ald, NN, 256);
    k_attn<<<wave_grid, 256, 0, stream>>>(hb, als, ald, off, csr, BI[0], yb, 1);

    // ---- layer 1 (K=128, relu) ----
    k_gemm<__bf16><<<gemm_grid, 256, 0, stream>>>(yb, Wt1, hb, AS[1], AD[1], als, ald, NN, HID);
    k_attn<<<wave_grid, 256, 0, stream>>>(hb, als, ald, off, csr, BI[1], yb, 1);

    // ---- layer 2 (K=128, no relu) ----
    k_gemm<__bf16><<<gemm_grid, 256, 0, stream>>>(yb, Wt2, hb, AS[2], AD[2], als, ald, NN, HID);
    k_attn<<<wave_grid, 256, 0, stream>>>(hb, als, ald, off, csr, BI[2], yb, 0);

    // ---- global mean pool ----
    k_pool<<<(NN + 127) / 128, 128, 0, stream>>>(yb, batch, sums);
    k_div<<<(NG * HID + 255) / 256, 256, 0, stream>>>(sums, batch, out);
}

// Round 10
// 330.301 us; speedup vs baseline: 1.0987x; 1.0433x over previous
//
#include <hip/hip_runtime.h>
#include <math.h>

// Problem constants (fixed by the reference setup)
#define NN 50000          // nodes
#define NE 800000         // edges (before self loops)
#define NTE (NE + NN)     // edges incl self loops
#define NG 16             // graphs
#define HID 128           // hidden/out dim (all layers out=128)
#define NEG_SLOPE 0.2f

#define NBUK 391          // ceil(NN/128) buckets of 128 dst nodes
#define EPW 4096          // edges per workgroup in bucket count/scatter
#define NWG_E ((NTE + EPW - 1) / EPW)   // 208
#define GEMM_GRID ((NN + 127) / 128)    // 391

typedef __attribute__((ext_vector_type(8))) __bf16 bf16x8;
typedef __attribute__((ext_vector_type(4))) float f32x4;

union V16 {
    float4 f4;
    uint4 u4;
    bf16x8 b8;
    __bf16 h[8];
};

// ---------------------------------------------------------------------------
// prep: zero bcnt/bwr/sums + all three weight transposes + off[NN], one dispatch.
// W [K][128] fp32 -> Wt [128][K] bf16
// ---------------------------------------------------------------------------
__global__ void k_prep(int* __restrict__ bcnt, int* __restrict__ bwr,
                       float* __restrict__ sums, int* __restrict__ off,
                       const float* __restrict__ W0, const float* __restrict__ W1,
                       const float* __restrict__ W2, __bf16* __restrict__ Wt0,
                       __bf16* __restrict__ Wt1, __bf16* __restrict__ Wt2) {
    int t = blockIdx.x * blockDim.x + threadIdx.x;
    if (t == 0) off[NN] = NTE;
    if (t <= NBUK) {
        bcnt[t] = 0;
        bwr[t] = 0;
    }
    if (t < NG * HID) sums[t] = 0.0f;
    if (t < 256 * HID) {
        int k = t >> 7, n = t & 127;
        Wt0[(size_t)n * 256 + k] = (__bf16)W0[t];
    } else if (t < 256 * HID + HID * HID) {
        int u = t - 256 * HID;
        int k = u >> 7, n = u & 127;
        Wt1[(size_t)n * HID + k] = (__bf16)W1[u];
    } else if (t < 256 * HID + 2 * HID * HID) {
        int u = t - 256 * HID - HID * HID;
        int k = u >> 7, n = u & 127;
        Wt2[(size_t)n * HID + k] = (__bf16)W2[u];
    }
}

// ---------------------------------------------------------------------------
// Bucketed CSR build.  rec[] holds src | (dst&127)<<17, grouped by bucket.
// ---------------------------------------------------------------------------
__global__ __launch_bounds__(256) void k_bcnt(const int* __restrict__ ei,
                                              int* __restrict__ bcnt) {
    __shared__ int hist[NBUK];
    int tid = threadIdx.x;
    for (int b = tid; b < NBUK; b += 256) hist[b] = 0;
    __syncthreads();
    int base = blockIdx.x * EPW;
    #pragma unroll
    for (int r = 0; r < EPW / 256; r++) {
        int idx = base + r * 256 + tid;
        if (idx < NTE) {
            int dst = (idx < NE) ? ei[NE + idx] : (idx - NE);
            atomicAdd(&hist[dst >> 7], 1);
        }
    }
    __syncthreads();
    for (int b = tid; b < NBUK; b += 256) {
        int c = hist[b];
        if (c) atomicAdd(&bcnt[b], c);
    }
}

// inclusive 512-scan of bcnt into s[] (LDS), 256 threads. s[i] = sum bcnt[0..i].
__device__ __forceinline__ void scan512(const int* __restrict__ bcnt, int* s) {
    int t = threadIdx.x;
    s[t] = (t < NBUK) ? bcnt[t] : 0;
    s[t + 256] = (t + 256 < NBUK) ? bcnt[t + 256] : 0;
    __syncthreads();
    for (int o = 1; o < 512; o <<= 1) {
        int a0 = (t >= o) ? s[t - o] : 0;
        int a1 = s[t + 256 - o];          // t+256 >= o always (o <= 256)
        __syncthreads();
        s[t] += a0;
        s[t + 256] += a1;
        __syncthreads();
    }
}

// scatter body: per-block hist -> chunk reservation -> packed record write
__device__ __forceinline__ void scatter_body(const int* __restrict__ ei,
                                             const int* __restrict__ bcnt,
                                             int* __restrict__ bwr,
                                             int* __restrict__ rec, int blk) {
    __shared__ int s[512];
    __shared__ int hist[NBUK];
    __shared__ int cur[NBUK];
    int t = threadIdx.x;
    scan512(bcnt, s);                      // s = inclusive scan of bcnt
    for (int b = t; b < NBUK; b += 256) hist[b] = 0;
    __syncthreads();
    int base = blk * EPW;
    #pragma unroll
    for (int r = 0; r < EPW / 256; r++) {
        int idx = base + r * 256 + t;
        if (idx < NTE) {
            int dst = (idx < NE) ? ei[NE + idx] : (idx - NE);
            atomicAdd(&hist[dst >> 7], 1);
        }
    }
    __syncthreads();
    for (int b = t; b < NBUK; b += 256) {
        int c = hist[b];
        if (c) cur[b] = (s[b] - bcnt[b]) + atomicAdd(&bwr[b], c);
    }
    __syncthreads();
    #pragma unroll
    for (int r = 0; r < EPW / 256; r++) {
        int idx = base + r * 256 + t;
        if (idx < NTE) {
            int src, dst;
            if (idx < NE) { src = ei[idx]; dst = ei[NE + idx]; }
            else          { src = idx - NE; dst = src; }
            int pos = atomicAdd(&cur[dst >> 7], 1);
            rec[pos] = src | ((dst & 127) << 17);
        }
    }
}

// one workgroup per bucket: inline scan -> window, local 128-scan -> off[],
// place src into csr window
__global__ __launch_bounds__(256) void k_bfill(const int* __restrict__ bcnt,
                                               const int* __restrict__ rec,
                                               int* __restrict__ off,
                                               int* __restrict__ csr) {
    __shared__ int s[512];
    __shared__ int cnt[128];
    __shared__ int scn[128];
    __shared__ int cur[128];
    int b = blockIdx.x, t = threadIdx.x;
    scan512(bcnt, s);
    int base = s[b] - bcnt[b];             // exclusive prefix (uniform)
    int n = bcnt[b];
    if (t < 128) cnt[t] = 0;
    __syncthreads();
    for (int i = t; i < n; i += 256) atomicAdd(&cnt[rec[base + i] >> 17], 1);
    __syncthreads();
    if (t < 128) scn[t] = cnt[t];
    __syncthreads();
    #pragma unroll
    for (int o = 1; o < 128; o <<= 1) {
        int add = (t >= o && t < 128) ? scn[t - o] : 0;
        __syncthreads();
        if (t < 128) scn[t] += add;
        __syncthreads();
    }
    if (t < 128) {
        int ex = scn[t] - cnt[t];
        cur[t] = ex;
        int d = b * 128 + t;
        if (d < NN) off[d] = base + ex;
    }
    __syncthreads();
    for (int i = t; i < n; i += 256) {
        int r = rec[base + i];
        int dloc = r >> 17;
        int src = r & 131071;
        int pos = atomicAdd(&cur[dloc], 1);
        csr[base + pos] = src;
    }
}

// ---------------------------------------------------------------------------
// MFMA GEMM body  C[M x 128] = A[M x K] * B[K x 128],  A row-major (fp32 or
// bf16, converted to bf16 during LDS staging), Bt = B^T bf16 [128 x K].
// C bf16 out.  BM=128, BN=128, BK=32.
// Fused epilogue: als[row]=dot(Crow,a_s), ald[row]=dot(Crow,a_d)
// ---------------------------------------------------------------------------
template <typename AT>
__device__ __forceinline__ void gemm_body(const AT* __restrict__ A,
                                          const __bf16* __restrict__ Bt,
                                          __bf16* __restrict__ C,
                                          const float* __restrict__ a_s,
                                          const float* __restrict__ a_d,
                                          float* __restrict__ als,
                                          float* __restrict__ ald,
                                          int M, int K, int blk) {
    __shared__ __align__(16) __bf16 As[128][40];   // padded: 80 B rows
    __shared__ __align__(16) __bf16 Bs[128][40];

    int tid = threadIdx.x;
    int rowBase = blk * 128;
    int wv = tid >> 6;        // wave 0..3
    int lane = tid & 63;
    int g = lane >> 4;        // k-slice selector (0..3)
    int c = lane & 15;        // col-in-tile / row-in-tile selector

    f32x4 acc[2][8];
    #pragma unroll
    for (int mi = 0; mi < 2; mi++)
        #pragma unroll
        for (int ni = 0; ni < 8; ni++) acc[mi][ni] = (f32x4){0.f, 0.f, 0.f, 0.f};

    for (int k0 = 0; k0 < K; k0 += 32) {
        __syncthreads();
        // stage A tile (convert to bf16 if AT==float)
        #pragma unroll
        for (int rep = 0; rep < 2; rep++) {
            int ch = tid + rep * 256;
            int r = ch >> 2, q = ch & 3;
            int row = rowBase + r;
            if constexpr (sizeof(AT) == 2) {
                float4 v = {0.f, 0.f, 0.f, 0.f};
                if (row < M) v = *(const float4*)((const __bf16*)A + (size_t)row * K + k0 + q * 8);
                *(float4*)&As[r][q * 8] = v;
            } else {
                float vv[8] = {0.f, 0.f, 0.f, 0.f, 0.f, 0.f, 0.f, 0.f};
                if (row < M) {
                    const float* Ap = (const float*)A + (size_t)row * K + k0 + q * 8;
                    float4 v0 = *(const float4*)Ap;
                    float4 v1 = *(const float4*)(Ap + 4);
                    vv[0] = v0.x; vv[1] = v0.y; vv[2] = v0.z; vv[3] = v0.w;
                    vv[4] = v1.x; vv[5] = v1.y; vv[6] = v1.z; vv[7] = v1.w;
                }
                V16 o;
                #pragma unroll
                for (int t = 0; t < 8; t++) o.h[t] = (__bf16)vv[t];
                *(float4*)&As[r][q * 8] = o.f4;
            }
        }
        // stage Bt tile
        #pragma unroll
        for (int rep = 0; rep < 2; rep++) {
            int ch = tid + rep * 256;
            int r = ch >> 2, q = ch & 3;
            float4 v = *(const float4*)(Bt + (size_t)r * K + k0 + q * 8);
            *(float4*)&Bs[r][q * 8] = v;
        }
        __syncthreads();

        bf16x8 a0 = *(const bf16x8*)&As[wv * 32 + c][g * 8];
        bf16x8 a1 = *(const bf16x8*)&As[wv * 32 + 16 + c][g * 8];
        #pragma unroll
        for (int ni = 0; ni < 8; ni++) {
            bf16x8 b = *(const bf16x8*)&Bs[ni * 16 + c][g * 8];
            acc[0][ni] = __builtin_amdgcn_mfma_f32_16x16x32_bf16(a0, b, acc[0][ni], 0, 0, 0);
            acc[1][ni] = __builtin_amdgcn_mfma_f32_16x16x32_bf16(a1, b, acc[1][ni], 0, 0, 0);
        }
    }

    float asv[8], adv[8];
    #pragma unroll
    for (int ni = 0; ni < 8; ni++) {
        asv[ni] = a_s[ni * 16 + c];
        adv[ni] = a_d[ni * 16 + c];
    }
    #pragma unroll
    for (int mi = 0; mi < 2; mi++) {
        int rb = rowBase + wv * 32 + mi * 16 + g * 4;
        #pragma unroll
        for (int i = 0; i < 4; i++) {
            int row = rb + i;
            float s = 0.f, dd = 0.f;
            #pragma unroll
            for (int ni = 0; ni < 8; ni++) {
                float v = acc[mi][ni][i];
                s = fmaf(v, asv[ni], s);
                dd = fmaf(v, adv[ni], dd);
            }
            #pragma unroll
            for (int o = 1; o <= 8; o <<= 1) {
                s += __shfl_xor(s, o);
                dd += __shfl_xor(dd, o);
            }
            if (row < M) {
                #pragma unroll
                for (int ni = 0; ni < 8; ni++)
                    C[(size_t)row * HID + ni * 16 + c] = (__bf16)acc[mi][ni][i];
                if (c == 0) {
                    als[row] = s;
                    ald[row] = dd;
                }
            }
        }
    }
}

// standalone GEMM (layers 1-2, bf16 A)
__global__ __launch_bounds__(256) void k_gemm_bf16(const __bf16* __restrict__ A,
                                                   const __bf16* __restrict__ Bt,
                                                   __bf16* __restrict__ C,
                                                   const float* __restrict__ a_s,
                                                   const float* __restrict__ a_d,
                                                   float* __restrict__ als,
                                                   float* __restrict__ ald) {
    gemm_body<__bf16>(A, Bt, C, a_s, a_d, als, ald, NN, HID, blockIdx.x);
}

// layer-0 GEMM (fp32 A, K=256) fused with CSR scatter (independent work):
// blocks [0, GEMM_GRID) do GEMM, the rest do scatter.
__global__ __launch_bounds__(256) void k_gemm0_scatter(const float* __restrict__ x,
                                                       const __bf16* __restrict__ Wt0,
                                                       __bf16* __restrict__ C,
                                                       const float* __restrict__ a_s,
                                                       const float* __restrict__ a_d,
                                                       float* __restrict__ als,
                                                       float* __restrict__ ald,
                                                       const int* __restrict__ ei,
                                                       const int* __restrict__ bcnt,
                                                       int* __restrict__ bwr,
                                                       int* __restrict__ rec) {
    if (blockIdx.x < GEMM_GRID) {
        gemm_body<float>(x, Wt0, C, a_s, a_d, als, ald, NN, 256, blockIdx.x);
    } else {
        scatter_body(ei, bcnt, bwr, rec, blockIdx.x - GEMM_GRID);
    }
}

// ---------------------------------------------------------------------------
// fused softmax + weighted gather: one wave per dst node.
// Phase 1: lane j handles edge e0+j; (src, cf-bits) packed into one LDS int2.
// Phase 2: 16-lane edge groups (4 edges in flight), one float4 (8 bf16) per
//   lane per edge; bf16->f32 via exact bit ops.
// ---------------------------------------------------------------------------
__global__ __launch_bounds__(256) void k_attn(const __bf16* __restrict__ h,
                                              const float* __restrict__ als,
                                              const float* __restrict__ ald,
                                              const int* __restrict__ off,
                                              const int* __restrict__ csr,
                                              const float* __restrict__ bias,
                                              __bf16* __restrict__ yout,
                                              int do_relu) {
    __shared__ int2 s_e[4][64];   // (src, cf bits) per wave
    int gt = blockIdx.x * blockDim.x + threadIdx.x;
    int d = gt >> 6;
    int lane = gt & 63;
    if (d >= NN) return;
    int wv = threadIdx.x >> 6;   // wave within block
    int grp = lane >> 4;         // edge slot 0..3
    int c = lane & 15;           // dim block (8 dims: c*8 .. c*8+7)

    int e0 = off[d], e1 = off[d + 1];
    int deg = e1 - e0;
    float ald_d = ald[d];
    float acc[8] = {0.f, 0.f, 0.f, 0.f, 0.f, 0.f, 0.f, 0.f};

    if (deg <= 64) {
        // ---- phase 1: softmax ----
        int s = 0;
        float e = -INFINITY;
        if (lane < deg) {
            s = csr[e0 + lane];
            float t = als[s] + ald_d;
            e = (t > 0.0f) ? t : NEG_SLOPE * t;
        }
        float mx = e;
        #pragma unroll
        for (int o = 32; o > 0; o >>= 1) mx = fmaxf(mx, __shfl_xor(mx, o));
        float p = (lane < deg) ? __expf(e - mx) : 0.0f;
        float z = p;
        #pragma unroll
        for (int o = 32; o > 0; o >>= 1) z += __shfl_xor(z, o);
        float inv_z = 1.0f / z;          // self loop guarantees z > 0
        s_e[wv][lane] = make_int2(s, __float_as_int(p * inv_z));

        // ---- phase 2: gather, 4 edges in flight ----
        #pragma unroll 4
        for (int k = grp; k < deg; k += 4) {
            int2 pr = s_e[wv][k];        // uniform within 16-lane group
            int ss = pr.x;
            float cf = __int_as_float(pr.y);
            V16 v;
            v.f4 = *(const float4*)(h + (size_t)ss * HID + c * 8);
            #pragma unroll
            for (int i = 0; i < 4; i++) {
                unsigned int u = (&v.u4.x)[i];
                float lo = __uint_as_float(u << 16);
                float hi = __uint_as_float(u & 0xffff0000u);
                acc[2 * i]     = fmaf(cf, lo, acc[2 * i]);
                acc[2 * i + 1] = fmaf(cf, hi, acc[2 * i + 1]);
            }
        }
    } else {
        // ---- rare slow path: strided two-pass + per-edge recompute ----
        float mx = -INFINITY;
        for (int j = e0 + lane; j < e1; j += 64) {
            float t = als[csr[j]] + ald_d;
            t = (t > 0.0f) ? t : NEG_SLOPE * t;
            mx = fmaxf(mx, t);
        }
        #pragma unroll
        for (int o = 32; o > 0; o >>= 1) mx = fmaxf(mx, __shfl_xor(mx, o));
        float z = 0.0f;
        for (int j = e0 + lane; j < e1; j += 64) {
            float t = als[csr[j]] + ald_d;
            t = (t > 0.0f) ? t : NEG_SLOPE * t;
            z += __expf(t - mx);
        }
        #pragma unroll
        for (int o = 32; o > 0; o >>= 1) z += __shfl_xor(z, o);
        float inv_z = 1.0f / z;
        for (int k = grp; k < deg; k += 4) {
            int ss = csr[e0 + k];
            float t = als[ss] + ald_d;
            t = (t > 0.0f) ? t : NEG_SLOPE * t;
            float cf = __expf(t - mx) * inv_z;
            V16 v;
            v.f4 = *(const float4*)(h + (size_t)ss * HID + c * 8);
            #pragma unroll
            for (int i = 0; i < 4; i++) {
                unsigned int u = (&v.u4.x)[i];
                float lo = __uint_as_float(u << 16);
                float hi = __uint_as_float(u & 0xffff0000u);
                acc[2 * i]     = fmaf(cf, lo, acc[2 * i]);
                acc[2 * i + 1] = fmaf(cf, hi, acc[2 * i + 1]);
            }
        }
    }

    // combine the 4 edge-groups
    #pragma unroll
    for (int t = 0; t < 8; t++) {
        acc[t] += __shfl_xor(acc[t], 16);
        acc[t] += __shfl_xor(acc[t], 32);
    }

    if (grp == 0) {
        float4 b0 = *(const float4*)(bias + c * 8);
        float4 b1 = *(const float4*)(bias + c * 8 + 4);
        acc[0] += b0.x; acc[1] += b0.y; acc[2] += b0.z; acc[3] += b0.w;
        acc[4] += b1.x; acc[5] += b1.y; acc[6] += b1.z; acc[7] += b1.w;
        if (do_relu) {
            #pragma unroll
            for (int t = 0; t < 8; t++) acc[t] = fmaxf(acc[t], 0.0f);
        }
        V16 o;
        #pragma unroll
        for (int t = 0; t < 8; t++) o.h[t] = (__bf16)acc[t];
        *(float4*)(yout + (size_t)d * HID + c * 8) = o.f4;
    }
}

// ---------------------------------------------------------------------------
// global mean pool: batch is sorted; per-block run-length accumulation.
// emb is bf16; accumulate fp32.
// ---------------------------------------------------------------------------
__global__ void k_pool(const __bf16* __restrict__ emb, const int* __restrict__ batch,
                       float* __restrict__ sums) {
    int t = threadIdx.x;          // dim
    int base = blockIdx.x * 128;
    int end = base + 128;
    if (end > NN) end = NN;
    float acc = 0.0f;
    int g_cur = -1;
    for (int n = base; n < end; ++n) {
        int g = batch[n];
        if (g != g_cur) {
            if (g_cur >= 0) atomicAdd(&sums[g_cur * HID + t], acc);
            acc = 0.0f;
            g_cur = g;
        }
        acc += (float)emb[(size_t)n * HID + t];
    }
    if (g_cur >= 0) atomicAdd(&sums[g_cur * HID + t], acc);
}

// counts via binary search on the sorted batch array
__global__ void k_div(const float* __restrict__ sums, const int* __restrict__ batch,
                      float* __restrict__ out) {
    int i = blockIdx.x * blockDim.x + threadIdx.x;
    if (i >= NG * HID) return;
    int g = i >> 7;
    int lo = 0, hi = NN;
    while (lo < hi) { int mid = (lo + hi) >> 1; if (batch[mid] < g) lo = mid + 1; else hi = mid; }
    int lo2 = lo, hi2 = NN;
    while (lo2 < hi2) { int mid = (lo2 + hi2) >> 1; if (batch[mid] < g + 1) lo2 = mid + 1; else hi2 = mid; }
    int c = lo2 - lo;
    out[i] = sums[i] / (float)(c > 1 ? c : 1);
}

// ---------------------------------------------------------------------------
extern "C" void kernel_launch(void* const* d_in, const int* in_sizes, int n_in,
                              void* d_out, int out_size, void* d_ws, size_t ws_size,
                              hipStream_t stream) {
    const float* x     = (const float*)d_in[0];   // [50000,256]
    const int*   ei    = (const int*)d_in[1];     // [2,800000]
    const int*   batch = (const int*)d_in[2];     // [50000]
    const float* W[3]  = {(const float*)d_in[3], (const float*)d_in[7], (const float*)d_in[11]};
    const float* AS[3] = {(const float*)d_in[4], (const float*)d_in[8], (const float*)d_in[12]};
    const float* AD[3] = {(const float*)d_in[5], (const float*)d_in[9], (const float*)d_in[13]};
    const float* BI[3] = {(const float*)d_in[6], (const float*)d_in[10], (const float*)d_in[14]};
    float* out = (float*)d_out;

    // workspace layout (~31 MB)
    char* ws = (char*)d_ws;
    size_t o = 0;
    auto alloc = [&](size_t bytes) {
        void* p = ws + o;
        o = (o + bytes + 255) & ~(size_t)255;
        return p;
    };
    __bf16* hb  = (__bf16*)alloc((size_t)NN * HID * 2);   // GEMM output (12.8 MB)
    __bf16* yb  = (__bf16*)alloc((size_t)NN * HID * 2);   // layer output bf16 (12.8 MB)
    __bf16* Wt0 = (__bf16*)alloc((size_t)256 * HID * 2);
    __bf16* Wt1 = (__bf16*)alloc((size_t)HID * HID * 2);
    __bf16* Wt2 = (__bf16*)alloc((size_t)HID * HID * 2);
    float* als  = (float*)alloc(NN * 4);
    float* ald  = (float*)alloc(NN * 4);
    int* off    = (int*)alloc((NN + 1) * 4);
    int* bcnt   = (int*)alloc((NBUK + 1) * 4);
    int* bwr    = (int*)alloc((NBUK + 1) * 4);
    int* rec    = (int*)alloc((size_t)NTE * 4);
    int* csr    = (int*)alloc((size_t)NTE * 4);
    float* sums = (float*)alloc(NG * HID * 4);
    (void)ws_size; (void)in_sizes; (void)n_in; (void)out_size;

    const int wave_grid = (NN * 64 + 255) / 256; // 12500

    // ---- prep: zero init + weight transposes + off[NN] (one dispatch) ----
    k_prep<<<(256 * HID + 2 * HID * HID + 255) / 256, 256, 0, stream>>>(
        bcnt, bwr, sums, off, W[0], W[1], W[2], Wt0, Wt1, Wt2);

    // ---- bucket counts ----
    k_bcnt<<<NWG_E, 256, 0, stream>>>(ei, bcnt);

    // ---- layer-0 GEMM fused with CSR scatter (independent work) ----
    k_gemm0_scatter<<<GEMM_GRID + NWG_E, 256, 0, stream>>>(
        x, Wt0, hb, AS[0], AD[0], als, ald, ei, bcnt, bwr, rec);

    // ---- CSR finalize ----
    k_bfill<<<NBUK, 256, 0, stream>>>(bcnt, rec, off, csr);

    // ---- layer 0 attention ----
    k_attn<<<wave_grid, 256, 0, stream>>>(hb, als, ald, off, csr, BI[0], yb, 1);

    // ---- layer 1 ----
    k_gemm_bf16<<<GEMM_GRID, 256, 0, stream>>>(yb, Wt1, hb, AS[1], AD[1], als, ald);
    k_attn<<<wave_grid, 256, 0, stream>>>(hb, als, ald, off, csr, BI[1], yb, 1);

    // ---- layer 2 ----
    k_gemm_bf16<<<GEMM_GRID, 256, 0, stream>>>(yb, Wt2, hb, AS[2], AD[2], als, ald);
    k_attn<<<wave_grid, 256, 0, stream>>>(hb, als, ald, off, csr, BI[2], yb, 0);

    // ---- global mean pool ----
    k_pool<<<(NN + 127) / 128, 128, 0, stream>>>(yb, batch, sums);
    k_div<<<(NG * HID + 255) / 256, 256, 0, stream>>>(sums, batch, out);
}